// Round 12
// baseline (195.284 us; speedup 1.0000x reference)
//
#include <hip/hip_runtime.h>
#include <math.h>

#define VOCAB 50000
#define VPAD  50048      // padded vocab rows (zeroed): no guards in hot loop
#define EMB   100
#define BATCH 2048
#define CTX   10

#define NVT   391        // 128-wide vocab tiles (391*128 = 50048)
#define BC    8          // batch chunks; block covers 256 b in 8 subtiles of 32
#define NMG   (VPAD / 16)   // 3128 16-row fragment groups
#define CVTB  (NMG / 4)     // 782 cvt blocks (4 mg each)
#define HBLK  (BATCH / 2)   // 1024 h blocks (2 b each)

#define LOG2E 1.44269504088896340736f

#if __has_builtin(__builtin_amdgcn_exp2f)
#define EXP2(x) __builtin_amdgcn_exp2f(x)
#else
#define EXP2(x) __expf((x) * 0.6931471805599453f)
#endif

// fp8 fragment order (K=128, lane L = q*16 + c16 holds k = q*32 + j, j=0..31):
//   ub8[(mg*64 + L)*32 + j]   mg = v>>4, c16 = v&15      (2 KB per 16 v-rows)
//   hb8[(bg*64 + L)*32 + j]   bg = b>>4, c16 = b&15      (2 KB per 16 b)
// u is PRE-SCALED by log2(e): scores arrive in the log2 domain -> raw v_exp_f32.

typedef __attribute__((ext_vector_type(8))) int   i32x8;
typedef __attribute__((ext_vector_type(4))) float f32x4;

// ---------------- prep: emb_u*log2e -> fp8 frag-order ub8 + h; zero neg_sum/out ----------------
__global__ __launch_bounds__(256)
void k_prep(const float* __restrict__ u, unsigned char* __restrict__ ub8,
            const int* __restrict__ x, const float* __restrict__ emb_v,
            float* __restrict__ hf, unsigned char* __restrict__ hb8,
            float* __restrict__ neg_sum, float* __restrict__ out) {
    const int blk = blockIdx.x;
    const int t   = threadIdx.x;
    if (blk < CVTB) {
        // ---- cvt: 4 mg groups per block; thread t writes 32 contiguous bytes ----
        const int mgid = blk * 4 + (t >> 6);
        const int L    = t & 63;
        const int c16  = L & 15;
        const int q    = L >> 4;
        const int row  = mgid * 16 + c16;
        const int e0   = q * 32;
        i32x8 o = (i32x8)0;
        if (row < VOCAB) {
            if (q < 3) {             // cols e0..e0+31 all valid
                const float4* p = (const float4*)&u[row * EMB + e0];
#pragma unroll
                for (int j = 0; j < 8; ++j) {
                    const float4 v = p[j];
                    int wd = __builtin_amdgcn_cvt_pk_fp8_f32(v.x * LOG2E, v.y * LOG2E, 0, false);
                    wd     = __builtin_amdgcn_cvt_pk_fp8_f32(v.z * LOG2E, v.w * LOG2E, wd, true);
                    o[j] = wd;
                }
            } else {                 // q==3: cols 96..99 valid, 100..127 zero
                const float4 v = *(const float4*)&u[row * EMB + 96];
                int wd = __builtin_amdgcn_cvt_pk_fp8_f32(v.x * LOG2E, v.y * LOG2E, 0, false);
                wd     = __builtin_amdgcn_cvt_pk_fp8_f32(v.z * LOG2E, v.w * LOG2E, wd, true);
                o[0] = wd;
            }
        }
        *(i32x8*)&ub8[((size_t)mgid * 64 + L) * 32] = o;   // coalesced: offset == t*32
    } else {
        // ---- h: 2 b per block; first 8 h-blocks also zero neg_sum ----
        const int hb = blk - CVTB;
        if (hb < 8) neg_sum[hb * 256 + t] = 0.0f;
        if (hb == 0 && t == 0) out[0] = 0.0f;
        const int b = hb * 2 + (t >> 7);
        const int e = t & 127;
        float s = 0.0f;
        if (e < EMB) {
#pragma unroll
            for (int c = 0; c < CTX; ++c) {
                const int idx = x[b * CTX + c];
                s += emb_v[idx * EMB + e];
            }
            s *= (1.0f / CTX);
            hf[b * EMB + e] = s;
        }
        const unsigned char f8 =
            (unsigned char)(__builtin_amdgcn_cvt_pk_fp8_f32(s, 0.0f, 0, false) & 0xFF);
        hb8[((b >> 4) * 64 + (e >> 5) * 16 + (b & 15)) * 32 + (e & 31)] = f8;
    }
}

// ---------------- fused MX-fp8 MFMA GEMM (K=128) + sigmoid row-sum ----------------
// A = u*log2e (m=v), B = h (n=b). D: col(lane&15)=b, row(q*4+reg)=v.
// Wave tile: 32 v-rows (mg = vy*8 + w*2 + mi), loop 8 subtiles of 32 b.
// acc 16 AGPR + af 16 + bf 16 VGPR -> fits 6 waves/EU. Folded sums go straight
// into neg_sum via atomicAdd (no partial array). NO LDS, NO barriers.
__global__ __launch_bounds__(256, 6)
void k_neg(const unsigned char* __restrict__ hb8, const unsigned char* __restrict__ ub8,
           float* __restrict__ neg_sum) {
    const int t  = threadIdx.x;
    const int w  = t >> 6;           // wave 0..3: v-range w*32 within the 128-v tile
    const int L  = t & 63;
    const int vy = blockIdx.y;

    // ---- A fragments: 2 x 32 B/lane, loaded once, reused all 8 subtiles ----
    i32x8 af[2];
#pragma unroll
    for (int mi = 0; mi < 2; ++mi)
        af[mi] = *(const i32x8*)&ub8[(((size_t)vy * 8 + w * 2 + mi) * 64 + L) * 32];

    const int b0base = blockIdx.x * (BATCH / BC);   // 256 b per block

#pragma unroll 1
    for (int bt = 0; bt < 8; ++bt) {   // 8 subtiles of 32 b
        const int b0  = b0base + bt * 32;
        const int Bg0 = b0 >> 4;

        i32x8 bf[2];
#pragma unroll
        for (int ni = 0; ni < 2; ++ni)
            bf[ni] = *(const i32x8*)&hb8[((size_t)(Bg0 + ni) * 64 + L) * 32];

        f32x4 acc[2][2];
#pragma unroll
        for (int mi = 0; mi < 2; ++mi)
#pragma unroll
            for (int ni = 0; ni < 2; ++ni) acc[mi][ni] = (f32x4)(0.0f);

#pragma unroll
        for (int mi = 0; mi < 2; ++mi)
#pragma unroll
            for (int ni = 0; ni < 2; ++ni)
                acc[mi][ni] = __builtin_amdgcn_mfma_scale_f32_16x16x128_f8f6f4(
                    af[mi], bf[ni], acc[mi][ni],
                    0, 0,                 // cbsz=fp8(e4m3), blgp=fp8(e4m3)
                    0, 0x7F7F7F7F,        // scale_a: 2^0
                    0, 0x7F7F7F7F);       // scale_b: 2^0

        // ---- epilogue: sum_v sigmoid(-score); log2-domain -> raw exp2; no guards ----
#pragma unroll
        for (int ni = 0; ni < 2; ++ni) {
            float p = 0.0f;
#pragma unroll
            for (int mi = 0; mi < 2; ++mi) {
                const float ea = EXP2(acc[mi][ni][0]);
                const float eb = EXP2(acc[mi][ni][1]);
                const float ec = EXP2(acc[mi][ni][2]);
                const float ed = EXP2(acc[mi][ni][3]);
                const float n1 = 2.0f + ea + eb;
                const float d1 = fmaf(ea, eb, n1 - 1.0f);
                const float n2 = 2.0f + ec + ed;
                const float d2 = fmaf(ec, ed, n2 - 1.0f);
                const float N  = fmaf(n1, d2, n2 * d1);
                p = fmaf(N, __builtin_amdgcn_rcpf(d1 * d2), p);
            }
            p += __shfl_down(p, 32);   // fold q
            p += __shfl_down(p, 16);
            if (L < 16)
                atomicAdd(&neg_sum[b0 + ni * 16 + L], p);
        }
    }
}

// ---------------- final: pos term + log(neg_sum - pad) + mean ----------------
__global__ void k_final(const int* __restrict__ y, const float* __restrict__ hf,
                        const float* __restrict__ u, const float* __restrict__ neg_sum,
                        float* __restrict__ out) {
    const int b = blockIdx.x * 256 + threadIdx.x;
    const float ns = neg_sum[b] - (float)(VPAD - VOCAB) * 0.5f;  // remove zero-pad rows

    const int yi = y[b];
    const float4* hp = (const float4*)&hf[b * EMB];
    const float4* up = (const float4*)&u[yi * EMB];
    float dot = 0.0f;
#pragma unroll
    for (int qq = 0; qq < EMB / 4; ++qq) {
        const float4 a = hp[qq];
        const float4 c = up[qq];
        dot += a.x * c.x + a.y * c.y + a.z * c.z + a.w * c.w;
    }
    const float pos = fmaxf(-dot, 0.0f) + log1pf(__expf(-fabsf(dot)));  // softplus(-dot)
    float val = pos + logf(ns);
#pragma unroll
    for (int off = 32; off; off >>= 1) val += __shfl_down(val, off, 64);
    if ((threadIdx.x & 63) == 0) atomicAdd(out, val * (1.0f / BATCH));
}

extern "C" void kernel_launch(void* const* d_in, const int* in_sizes, int n_in,
                              void* d_out, int out_size, void* d_ws, size_t ws_size,
                              hipStream_t stream) {
    const int*   x     = (const int*)d_in[0];
    const int*   y     = (const int*)d_in[1];
    const float* emb_v = (const float*)d_in[2];
    const float* emb_u = (const float*)d_in[3];
    float* out = (float*)d_out;

    // workspace carve (~7.5 MB), 32B-aligned sections
    float*         hf      = (float*)d_ws;                           // 2048*100 fp32
    float*         neg_sum = hf + BATCH * EMB;                       // 2048 fp32
    unsigned char* hb8     = (unsigned char*)(neg_sum + BATCH);      // 128*2048 B
    unsigned char* ub8     = hb8 + (size_t)(BATCH / 16) * 2048;      // 3128*2048 B

    k_prep <<<dim3(CVTB + HBLK), dim3(256), 0, stream>>>(emb_u, ub8, x, emb_v, hf, hb8, neg_sum, out);
    k_neg  <<<dim3(BC, NVT), dim3(256), 0, stream>>>(hb8, ub8, neg_sum);
    k_final<<<dim3(BATCH / 256), dim3(256), 0, stream>>>(y, hf, emb_u, neg_sum, out);
}

// Round 13
// 147.874 us; speedup vs baseline: 1.3206x; 1.3206x over previous
//
#include <hip/hip_runtime.h>
#include <math.h>

#define VOCAB 50000
#define VPAD  50048      // padded vocab rows (zeroed): no guards in hot loop
#define EMB   100
#define BATCH 2048
#define CTX   10

#define NVT   391        // 128-wide vocab tiles (391*128 = 50048)
#define BC    8          // batch chunks; block covers 256 b in 8 subtiles of 32
#define PROWS (4 * NVT)  // partial rows: (vy, wave) = 1564
#define NMG   (VPAD / 16)   // 3128 16-row fragment groups
#define CVTB  (NMG / 4)     // 782 cvt blocks (4 mg each)
#define HBLK  (BATCH / 2)   // 1024 h blocks (2 b each)

#define LOG2E 1.44269504088896340736f

#if __has_builtin(__builtin_amdgcn_exp2f)
#define EXP2(x) __builtin_amdgcn_exp2f(x)
#else
#define EXP2(x) __expf((x) * 0.6931471805599453f)
#endif

// fp8 fragment order (K=128, lane L = q*16 + c16 holds k = q*32 + j, j=0..31):
//   ub8[(mg*64 + L)*32 + j]   mg = v>>4, c16 = v&15      (2 KB per 16 v-rows)
//   hb8[(bg*64 + L)*32 + j]   bg = b>>4, c16 = b&15      (2 KB per 16 b)
// u is PRE-SCALED by log2(e): scores arrive in the log2 domain -> raw v_exp_f32.

typedef __attribute__((ext_vector_type(8))) int   i32x8;
typedef __attribute__((ext_vector_type(4))) float f32x4;

// ---------------- prep: emb_u*log2e -> fp8 frag-order ub8 + h (fp32 + fp8) ----------------
__global__ __launch_bounds__(256)
void k_prep(const float* __restrict__ u, unsigned char* __restrict__ ub8,
            const int* __restrict__ x, const float* __restrict__ emb_v,
            float* __restrict__ hf, unsigned char* __restrict__ hb8,
            float* __restrict__ out) {
    const int blk = blockIdx.x;
    const int t   = threadIdx.x;
    if (blk < CVTB) {
        // ---- cvt: 4 mg groups per block; thread t writes 32 contiguous bytes ----
        const int mgid = blk * 4 + (t >> 6);
        const int L    = t & 63;
        const int c16  = L & 15;
        const int q    = L >> 4;
        const int row  = mgid * 16 + c16;
        const int e0   = q * 32;
        i32x8 o = (i32x8)0;
        if (row < VOCAB) {
            if (q < 3) {             // cols e0..e0+31 all valid
                const float4* p = (const float4*)&u[row * EMB + e0];
#pragma unroll
                for (int j = 0; j < 8; ++j) {
                    const float4 v = p[j];
                    int wd = __builtin_amdgcn_cvt_pk_fp8_f32(v.x * LOG2E, v.y * LOG2E, 0, false);
                    wd     = __builtin_amdgcn_cvt_pk_fp8_f32(v.z * LOG2E, v.w * LOG2E, wd, true);
                    o[j] = wd;
                }
            } else {                 // q==3: cols 96..99 valid, 100..127 zero
                const float4 v = *(const float4*)&u[row * EMB + 96];
                int wd = __builtin_amdgcn_cvt_pk_fp8_f32(v.x * LOG2E, v.y * LOG2E, 0, false);
                wd     = __builtin_amdgcn_cvt_pk_fp8_f32(v.z * LOG2E, v.w * LOG2E, wd, true);
                o[0] = wd;
            }
        }
        *(i32x8*)&ub8[((size_t)mgid * 64 + L) * 32] = o;   // coalesced: offset == t*32
    } else {
        // ---- h: 2 b per block ----
        const int b = (blk - CVTB) * 2 + (t >> 7);
        const int e = t & 127;
        if (blk == CVTB && t == 0) out[0] = 0.0f;
        float s = 0.0f;
        if (e < EMB) {
#pragma unroll
            for (int c = 0; c < CTX; ++c) {
                const int idx = x[b * CTX + c];
                s += emb_v[idx * EMB + e];
            }
            s *= (1.0f / CTX);
            hf[b * EMB + e] = s;
        }
        const unsigned char f8 =
            (unsigned char)(__builtin_amdgcn_cvt_pk_fp8_f32(s, 0.0f, 0, false) & 0xFF);
        hb8[((b >> 4) * 64 + (e >> 5) * 16 + (b & 15)) * 32 + (e & 31)] = f8;
    }
}

// ---------------- fused MX-fp8 MFMA GEMM (K=128) + sigmoid row-sum ----------------
// A = u*log2e (m=v), B = h (n=b). D: col(lane&15)=b, row(q*4+reg)=v.
// Wave tile: 32 v-rows (mg = vy*8 + w*2 + mi), loop 8 subtiles of 32 b.
// Tiny register footprint (acc 16 AGPR + af/bf 32 VGPR) -> high occupancy.
// Wave-disjoint partial[4*vy + w] rows: NO atomics, NO LDS, NO barriers.
__global__ __launch_bounds__(256, 6)
void k_neg(const unsigned char* __restrict__ hb8, const unsigned char* __restrict__ ub8,
           float* __restrict__ partial) {
    const int t  = threadIdx.x;
    const int w  = t >> 6;           // wave 0..3: v-range w*32 within the 128-v tile
    const int L  = t & 63;
    const int vy = blockIdx.y;

    // ---- A fragments: 2 x 32 B/lane, loaded once, reused all 8 subtiles ----
    i32x8 af[2];
#pragma unroll
    for (int mi = 0; mi < 2; ++mi)
        af[mi] = *(const i32x8*)&ub8[(((size_t)vy * 8 + w * 2 + mi) * 64 + L) * 32];

    const int b0base = blockIdx.x * (BATCH / BC);   // 256 b per block
    const int prow   = (4 * vy + w) * BATCH;

#pragma unroll 1
    for (int bt = 0; bt < 8; ++bt) {   // 8 subtiles of 32 b
        const int b0  = b0base + bt * 32;
        const int Bg0 = b0 >> 4;

        i32x8 bf[2];
#pragma unroll
        for (int ni = 0; ni < 2; ++ni)
            bf[ni] = *(const i32x8*)&hb8[((size_t)(Bg0 + ni) * 64 + L) * 32];

        f32x4 acc[2][2];
#pragma unroll
        for (int mi = 0; mi < 2; ++mi)
#pragma unroll
            for (int ni = 0; ni < 2; ++ni) acc[mi][ni] = (f32x4)(0.0f);

#pragma unroll
        for (int mi = 0; mi < 2; ++mi)
#pragma unroll
            for (int ni = 0; ni < 2; ++ni)
                acc[mi][ni] = __builtin_amdgcn_mfma_scale_f32_16x16x128_f8f6f4(
                    af[mi], bf[ni], acc[mi][ni],
                    0, 0,                 // cbsz=fp8(e4m3), blgp=fp8(e4m3)
                    0, 0x7F7F7F7F,        // scale_a: 2^0
                    0, 0x7F7F7F7F);       // scale_b: 2^0

        // ---- epilogue: sum_v sigmoid(-score); log2-domain -> raw exp2; no guards ----
#pragma unroll
        for (int ni = 0; ni < 2; ++ni) {
            float p = 0.0f;
#pragma unroll
            for (int mi = 0; mi < 2; ++mi) {
                const float ea = EXP2(acc[mi][ni][0]);
                const float eb = EXP2(acc[mi][ni][1]);
                const float ec = EXP2(acc[mi][ni][2]);
                const float ed = EXP2(acc[mi][ni][3]);
                const float n1 = 2.0f + ea + eb;
                const float d1 = fmaf(ea, eb, n1 - 1.0f);
                const float n2 = 2.0f + ec + ed;
                const float d2 = fmaf(ec, ed, n2 - 1.0f);
                const float N  = fmaf(n1, d2, n2 * d1);
                p = fmaf(N, __builtin_amdgcn_rcpf(d1 * d2), p);
            }
            p += __shfl_down(p, 32);   // fold q
            p += __shfl_down(p, 16);
            if (L < 16)
                partial[prow + b0 + ni * 16 + L] = p;   // coalesced 64 B store
        }
    }
}

// ---------------- reduce partial rows + pos term + mean ----------------
// 32 blocks x 1024 threads: 64 b-lanes x 16 row-waves, coalesced across b.
__global__ void k_redfinal(const int* __restrict__ y, const float* __restrict__ hf,
                           const float* __restrict__ u, const float* __restrict__ partial,
                           float* __restrict__ out) {
    const int t    = threadIdx.x;
    const int lane = t & 63;
    const int w    = t >> 6;          // 0..15
    const int b    = blockIdx.x * 64 + lane;
    float s = 0.0f;
    for (int r = w; r < PROWS; r += 16)
        s += partial[r * BATCH + b];  // coalesced across 64 lanes
    __shared__ float red[16][64];
    red[w][lane] = s;
    __syncthreads();
    if (w == 0) {
        float ns = -(float)(VPAD - VOCAB) * 0.5f;   // remove zero-pad rows (exact 0.5 each)
#pragma unroll
        for (int i = 0; i < 16; ++i) ns += red[i][lane];

        const int yi = y[b];
        const float4* hp = (const float4*)&hf[b * EMB];
        const float4* up = (const float4*)&u[yi * EMB];
        float dot = 0.0f;
#pragma unroll
        for (int qq = 0; qq < EMB / 4; ++qq) {
            const float4 a = hp[qq];
            const float4 c = up[qq];
            dot += a.x * c.x + a.y * c.y + a.z * c.z + a.w * c.w;
        }
        const float pos = fmaxf(-dot, 0.0f) + log1pf(__expf(-fabsf(dot)));  // softplus(-dot)
        float val = pos + logf(ns);
#pragma unroll
        for (int off = 32; off; off >>= 1) val += __shfl_down(val, off, 64);
        if (lane == 0) atomicAdd(out, val * (1.0f / BATCH));
    }
}

extern "C" void kernel_launch(void* const* d_in, const int* in_sizes, int n_in,
                              void* d_out, int out_size, void* d_ws, size_t ws_size,
                              hipStream_t stream) {
    const int*   x     = (const int*)d_in[0];
    const int*   y     = (const int*)d_in[1];
    const float* emb_v = (const float*)d_in[2];
    const float* emb_u = (const float*)d_in[3];
    float* out = (float*)d_out;

    // workspace carve (~20.5 MB), 32B-aligned sections
    float*         hf      = (float*)d_ws;                           // 2048*100 fp32
    float*         partial = hf + BATCH * EMB;                       // 1564*2048 fp32
    unsigned char* hb8     = (unsigned char*)(partial + PROWS * BATCH);  // 128*2048 B
    unsigned char* ub8     = hb8 + (size_t)(BATCH / 16) * 2048;      // 3128*2048 B

    k_prep    <<<dim3(CVTB + HBLK), dim3(256), 0, stream>>>(emb_u, ub8, x, emb_v, hf, hb8, out);
    k_neg     <<<dim3(BC, NVT), dim3(256), 0, stream>>>(hb8, ub8, partial);
    k_redfinal<<<dim3(BATCH / 64), dim3(1024), 0, stream>>>(y, hf, emb_u, partial, out);
}

// Round 14
// 129.414 us; speedup vs baseline: 1.5090x; 1.1426x over previous
//
#include <hip/hip_runtime.h>
#include <math.h>

#define VOCAB 50000
#define VPAD  50048      // padded vocab rows (zeroed): no guards in hot loop
#define EMB   100
#define BATCH 2048
#define CTX   10

#define NVT   391        // 128-wide vocab tiles (391*128 = 50048)
#define BC    8          // batch chunks; block covers 256 b in 4 subtiles of 64
#define PROWS (2 * NVT)  // partial rows: (vy, v-half) = 782
#define NMG   (VPAD / 16)   // 3128 16-row fragment groups
#define CVTB  (NMG / 4)     // 782 cvt blocks (4 mg each)
#define HBLK  (BATCH / 2)   // 1024 h blocks (2 b each)

#define LOG2E 1.44269504088896340736f

#if __has_builtin(__builtin_amdgcn_exp2f)
#define EXP2(x) __builtin_amdgcn_exp2f(x)
#else
#define EXP2(x) __expf((x) * 0.6931471805599453f)
#endif

// fp8 fragment order (K=128, lane L = q*16 + c16 holds k = q*32 + j, j=0..31):
//   ub8[(mg*64 + L)*32 + j]   mg = v>>4, c16 = v&15      (2 KB per 16 v-rows)
//   hb8[(bg*64 + L)*32 + j]   bg = b>>4, c16 = b&15      (2 KB per 16 b)
// -> every A/B fragment load is 64 lanes x 32 B CONTIGUOUS (2 KB).
// u is PRE-SCALED by log2(e): GEMM emits scores in the log2 domain, so the
// sigmoid epilogue needs only raw v_exp_f32 (2^x), no per-element multiply.

typedef __attribute__((ext_vector_type(8))) int   i32x8;
typedef __attribute__((ext_vector_type(4))) float f32x4;

// ---------------- prep: emb_u*log2e -> fp8 frag-order ub8 + h (fp32 + fp8 frag-order) ----------------
__global__ __launch_bounds__(256)
void k_prep(const float* __restrict__ u, unsigned char* __restrict__ ub8,
            const int* __restrict__ x, const float* __restrict__ emb_v,
            float* __restrict__ hf, unsigned char* __restrict__ hb8,
            float* __restrict__ out) {
    const int blk = blockIdx.x;
    const int t   = threadIdx.x;
    if (blk < CVTB) {
        // ---- cvt: 4 mg groups per block; thread t writes 32 contiguous bytes ----
        const int mgid = blk * 4 + (t >> 6);
        const int L    = t & 63;
        const int c16  = L & 15;
        const int q    = L >> 4;
        const int row  = mgid * 16 + c16;
        const int e0   = q * 32;
        i32x8 o = (i32x8)0;
        if (row < VOCAB) {
            if (q < 3) {             // cols e0..e0+31 all valid
                const float4* p = (const float4*)&u[row * EMB + e0];
#pragma unroll
                for (int j = 0; j < 8; ++j) {
                    const float4 v = p[j];
                    int wd = __builtin_amdgcn_cvt_pk_fp8_f32(v.x * LOG2E, v.y * LOG2E, 0, false);
                    wd     = __builtin_amdgcn_cvt_pk_fp8_f32(v.z * LOG2E, v.w * LOG2E, wd, true);
                    o[j] = wd;
                }
            } else {                 // q==3: cols 96..99 valid, 100..127 zero
                const float4 v = *(const float4*)&u[row * EMB + 96];
                int wd = __builtin_amdgcn_cvt_pk_fp8_f32(v.x * LOG2E, v.y * LOG2E, 0, false);
                wd     = __builtin_amdgcn_cvt_pk_fp8_f32(v.z * LOG2E, v.w * LOG2E, wd, true);
                o[0] = wd;
            }
        }
        *(i32x8*)&ub8[((size_t)mgid * 64 + L) * 32] = o;   // coalesced: offset == t*32
    } else {
        // ---- h: 2 b per block ----
        const int b = (blk - CVTB) * 2 + (t >> 7);
        const int e = t & 127;
        if (blk == CVTB && t == 0) out[0] = 0.0f;
        float s = 0.0f;
        if (e < EMB) {
#pragma unroll
            for (int c = 0; c < CTX; ++c) {
                const int idx = x[b * CTX + c];
                s += emb_v[idx * EMB + e];
            }
            s *= (1.0f / CTX);
            hf[b * EMB + e] = s;
        }
        const unsigned char f8 =
            (unsigned char)(__builtin_amdgcn_cvt_pk_fp8_f32(s, 0.0f, 0, false) & 0xFF);
        hb8[((b >> 4) * 64 + (e >> 5) * 16 + (b & 15)) * 32 + (e & 31)] = f8;
    }
}

// ---------------- fused MX-fp8 MFMA GEMM (K=128 per instr) + sigmoid row-sum ----------------
// A = u*log2e (m=v), B = h (n=b). D: col(lane&15)=b, row(q*4+reg)=v.
// Unit E8M0 scales. A-frags cached in 32 VGPRs; bf software-pipelined one subtile
// ahead so trans-heavy epilogue covers load latency. NO LDS, NO barriers, NO atomics.
__global__ __launch_bounds__(256, 4)
void k_neg(const unsigned char* __restrict__ hb8, const unsigned char* __restrict__ ub8,
           float* __restrict__ partial) {
    const int t   = threadIdx.x;
    const int w   = t >> 6;          // wave 0..3
    const int L   = t & 63;
    const int wvh = w & 1;           // v half: mg 0..3 or 4..7 of the 128-v tile
    const int wbh = w >> 1;          // b half within 64-b subtile
    const int vy  = blockIdx.y;

    // ---- A fragments: 4 x 32 B/lane, loaded once, reused all subtiles ----
    i32x8 af[4];
#pragma unroll
    for (int mi = 0; mi < 4; ++mi)
        af[mi] = *(const i32x8*)&ub8[(((size_t)vy * 8 + wvh * 4 + mi) * 64 + L) * 32];

    const int b0base = blockIdx.x * (BATCH / BC);   // 256 b per block
    const int prow   = (2 * vy + wvh) * BATCH;
    const int NT     = (BATCH / BC) / 64;           // 4 subtiles

    // ---- prefetch bt=0 b-fragments ----
    i32x8 bf[2];
#pragma unroll
    for (int ni = 0; ni < 2; ++ni)
        bf[ni] = *(const i32x8*)&hb8[((size_t)((b0base >> 4) + wbh * 2 + ni) * 64 + L) * 32];

#pragma unroll 1
    for (int bt = 0; bt < NT; ++bt) {
        const int b0 = b0base + bt * 64;

        f32x4 acc[4][2];
#pragma unroll
        for (int mi = 0; mi < 4; ++mi)
#pragma unroll
            for (int ni = 0; ni < 2; ++ni) acc[mi][ni] = (f32x4)(0.0f);

#pragma unroll
        for (int mi = 0; mi < 4; ++mi)
#pragma unroll
            for (int ni = 0; ni < 2; ++ni)
                acc[mi][ni] = __builtin_amdgcn_mfma_scale_f32_16x16x128_f8f6f4(
                    af[mi], bf[ni], acc[mi][ni],
                    0, 0,                 // cbsz=fp8(e4m3), blgp=fp8(e4m3)
                    0, 0x7F7F7F7F,        // scale_a: 2^0
                    0, 0x7F7F7F7F);       // scale_b: 2^0

        // ---- prefetch next subtile's bf (clamped index; overlaps epilogue) ----
        const int btn = (bt + 1 < NT) ? bt + 1 : bt;
        const int Bgn = (b0base + btn * 64) >> 4;
#pragma unroll
        for (int ni = 0; ni < 2; ++ni)
            bf[ni] = *(const i32x8*)&hb8[((size_t)(Bgn + wbh * 2 + ni) * 64 + L) * 32];

        // ---- epilogue: sum_v sigmoid(-score); scores in log2 domain -> raw exp2 ----
#pragma unroll
        for (int ni = 0; ni < 2; ++ni) {
            float p = 0.0f;
#pragma unroll
            for (int mi = 0; mi < 4; ++mi) {
                const float ea = EXP2(acc[mi][ni][0]);
                const float eb = EXP2(acc[mi][ni][1]);
                const float ec = EXP2(acc[mi][ni][2]);
                const float ed = EXP2(acc[mi][ni][3]);
                const float n1 = 2.0f + ea + eb;
                const float d1 = fmaf(ea, eb, n1 - 1.0f);
                const float n2 = 2.0f + ec + ed;
                const float d2 = fmaf(ec, ed, n2 - 1.0f);
                const float N  = fmaf(n1, d2, n2 * d1);
                p = fmaf(N, __builtin_amdgcn_rcpf(d1 * d2), p);
            }
            p += __shfl_down(p, 32);   // fold q
            p += __shfl_down(p, 16);
            if (L < 16)
                partial[prow + b0 + wbh * 32 + ni * 16 + L] = p;
        }
    }
}

// ---------------- reduce partial rows + pos term + mean ----------------
__global__ void k_redfinal(const int* __restrict__ y, const float* __restrict__ hf,
                           const float* __restrict__ u, const float* __restrict__ partial,
                           float* __restrict__ out) {
    const int t    = threadIdx.x;
    const int lane = t & 63;
    const int w    = t >> 6;          // 0..15
    const int b    = blockIdx.x * 64 + lane;
    float s = 0.0f;
    for (int r = w; r < PROWS; r += 16)
        s += partial[r * BATCH + b];  // coalesced across 64 lanes
    __shared__ float red[16][64];
    red[w][lane] = s;
    __syncthreads();
    if (w == 0) {
        float ns = -(float)(VPAD - VOCAB) * 0.5f;   // remove zero-pad rows (exact 0.5 each)
#pragma unroll
        for (int i = 0; i < 16; ++i) ns += red[i][lane];

        const int yi = y[b];
        const float4* hp = (const float4*)&hf[b * EMB];
        const float4* up = (const float4*)&u[yi * EMB];
        float dot = 0.0f;
#pragma unroll
        for (int qq = 0; qq < EMB / 4; ++qq) {
            const float4 a = hp[qq];
            const float4 c = up[qq];
            dot += a.x * c.x + a.y * c.y + a.z * c.z + a.w * c.w;
        }
        const float pos = fmaxf(-dot, 0.0f) + log1pf(__expf(-fabsf(dot)));  // softplus(-dot)
        float val = pos + logf(ns);
#pragma unroll
        for (int off = 32; off; off >>= 1) val += __shfl_down(val, off, 64);
        if (lane == 0) atomicAdd(out, val * (1.0f / BATCH));
    }
}

extern "C" void kernel_launch(void* const* d_in, const int* in_sizes, int n_in,
                              void* d_out, int out_size, void* d_ws, size_t ws_size,
                              hipStream_t stream) {
    const int*   x     = (const int*)d_in[0];
    const int*   y     = (const int*)d_in[1];
    const float* emb_v = (const float*)d_in[2];
    const float* emb_u = (const float*)d_in[3];
    float* out = (float*)d_out;

    // workspace carve (~14 MB), 32B-aligned sections
    float*         hf      = (float*)d_ws;                            // 2048*100 fp32
    float*         partial = hf + BATCH * EMB;                        // 782*2048 fp32
    unsigned char* hb8     = (unsigned char*)(partial + PROWS * BATCH);  // 128*2048 B
    unsigned char* ub8     = hb8 + (size_t)(BATCH / 16) * 2048;       // 3128*2048 B

    k_prep    <<<dim3(CVTB + HBLK), dim3(256), 0, stream>>>(emb_u, ub8, x, emb_v, hf, hb8, out);
    k_neg     <<<dim3(BC, NVT), dim3(256), 0, stream>>>(hb8, ub8, partial);
    k_redfinal<<<dim3(BATCH / 64), dim3(1024), 0, stream>>>(y, hf, emb_u, partial, out);
}